// Round 3
// baseline (1066.597 us; speedup 1.0000x reference)
//
#include <hip/hip_runtime.h>
#include <hip/hip_bf16.h>

#define DEV __device__ __forceinline__

// Problem constants
constexpr int Cc = 64, DIc = 128, Sc = 16, Rc = 4, Kc = 4;
constexpr int Hh = 48, Ww = 48, Lc = 2304, Tc = 4;
constexpr int NCH = 48, CHL = 48;   // 48 chunks of length 48 (48*48 = 2304)

// Workspace layout (float offsets). ONE slot, reused by all 8 SS2D rounds.
// Total footprint: 5,357,568 floats = 21.4 MB.
constexpr int OFF_XCPRE = 0;              // L*DI  [l][d]  xz first half (pre-conv)
constexpr int OFF_Z     = 294912;         // L*DI  [l][d]
constexpr int OFF_XACT  = 589824;         // L*DI  [l][d]  conv+silu output
constexpr int OFF_DT    = 884736;         // K*L*DI [k][l][d] (l = scan position)
constexpr int OFF_BS    = 2064384;        // K*L*S  [k][l][s]
constexpr int OFF_CS    = 2211840;        // K*L*S
constexpr int OFF_Y     = 2359296;        // K*L*DI [k][l][d]
constexpr int OFF_SUMA  = 3538944;        // K*NCH*DI*S [k][ch][d][s]
constexpr int OFF_SUMB  = 3932160;        // K*NCH*DI*S
constexpr int OFF_B0    = 4325376;        // L*C state buffers [l][c]
constexpr int OFF_B1    = OFF_B0 + Lc * Cc;
constexpr int OFF_B2    = OFF_B1 + Lc * Cc;
constexpr int OFF_BIAS  = OFF_B2 + Lc * Cc;       // T*L*C [t][l][c]

DEV float wsum(float v) {
#pragma unroll
  for (int m = 32; m; m >>= 1) v += __shfl_xor(v, m, 64);
  return v;
}
DEV float wmax(float v) {
#pragma unroll
  for (int m = 32; m; m >>= 1) v = fmaxf(v, __shfl_xor(v, m, 64));
  return v;
}
DEV float sigmoidf(float x) { return 1.f / (1.f + __expf(-x)); }

// ---------------------------------------------------------------------------
// prep: prev = LN_c(difficult_zone); cur = prev * exp(sigma)
// block = 256 (4 waves = 4 pixels), grid = 576
__global__ __launch_bounds__(256) void k_prep(const float* dz, const float* sigma,
                                              const float* ndw, const float* ndb,
                                              float* ws) {
  int tid = threadIdx.x;
  int wv = tid >> 6, c = tid & 63;
  int l = blockIdx.x * 4 + wv;
  float* prevb = ws + OFF_B0;
  float* curb  = ws + OFF_B1;
  float v = dz[c * Lc + l];
  float mu = wsum(v) * (1.f / 64.f);
  float var = wsum(v * v) * (1.f / 64.f) - mu * mu;
  float pv = (v - mu) * rsqrtf(var + 1e-6f) * ndw[c] + ndb[c];
  prevb[l * Cc + c] = pv;
  curb[l * Cc + c] = pv * __expf(sigma[c * Lc + l]);
}

// ---------------------------------------------------------------------------
// input projection: x -> xz = in_w @ x + in_b, split into xcpre / z.
// mode 0: x = LN_c(image_sequence[tstep]); mode 1: x = KL(cur, prev)
// block = 256, 8 pixels per block, grid.x = 288
__global__ __launch_bounds__(256) void k_inproj(const float* img, const float* niw,
                                                const float* nib, const float* curb,
                                                const float* prevb, const float* in_w,
                                                const float* in_b, int branch, int mode,
                                                int tstep, float* ws) {
  __shared__ float xv[8][64];
  int tid = threadIdx.x;
  float* xcpre = ws + OFF_XCPRE;
  float* zbuf  = ws + OFF_Z;
  int l0 = blockIdx.x * 8;
  int wv = tid >> 6, c = tid & 63;
#pragma unroll
  for (int q = 0; q < 2; q++) {
    int p = wv * 2 + q;
    int l = l0 + p;
    float x;
    if (mode == 0) {
      float v = img[(tstep * Cc + c) * Lc + l];
      float mu = wsum(v) * (1.f / 64.f);
      float var = wsum(v * v) * (1.f / 64.f) - mu * mu;
      x = (v - mu) * rsqrtf(var + 1e-6f) * niw[c] + nib[c];
    } else {
      float pv = prevb[l * Cc + c], cv = curb[l * Cc + c];
      float mp = wmax(pv);
      float sp = wsum(__expf(pv - mp));
      float lp = pv - mp - __logf(sp);
      float mq = wmax(cv);
      float sq = wsum(__expf(cv - mq));
      float lq = cv - mq - __logf(sq);
      x = __expf(lp) * (lp - lq);
    }
    xv[p][c] = x;
  }
  __syncthreads();
  int d = tid;  // 0..255 output rows
  float acc[8];
#pragma unroll
  for (int p = 0; p < 8; p++) acc[p] = 0.f;
  const float* wrow = in_w + (branch * 2 * DIc + d) * Cc;
  for (int cc = 0; cc < Cc; cc++) {
    float wval = wrow[cc];
#pragma unroll
    for (int p = 0; p < 8; p++) acc[p] += wval * xv[p][cc];
  }
  float bv = in_b[branch * 2 * DIc + d];
  if (d < DIc) {
#pragma unroll
    for (int p = 0; p < 8; p++) xcpre[(l0 + p) * DIc + d] = acc[p] + bv;
  } else {
    int dd = d - DIc;
#pragma unroll
    for (int p = 0; p < 8; p++) zbuf[(l0 + p) * DIc + dd] = acc[p] + bv;
  }
}

// ---------------------------------------------------------------------------
// depthwise conv3x3 + silu -> xact; xp proj -> dts/Bs/Cs; dt proj + softplus -> dt
// block = 256, 4 pixels (same row) per block, grid.x = 576
__global__ __launch_bounds__(256) void k_conv_proj(const float* conv_w, const float* conv_b,
                                                   const float* xp_w, const float* dt_w,
                                                   const float* dt_b, int branch, float* ws) {
  __shared__ float xv[4][DIc];
  __shared__ float dts[4][Kc][Rc];
  int tid = threadIdx.x;
  float* xcpre = ws + OFF_XCPRE;
  float* xact  = ws + OFF_XACT;
  float* dtg   = ws + OFF_DT;
  float* Bsb   = ws + OFF_BS;
  float* Csb   = ws + OFF_CS;
  int h = blockIdx.x / 12;
  int w0 = (blockIdx.x % 12) * 4;
  // phase 0: conv + silu (4 px x 128 ch)
  for (int it = tid; it < 4 * DIc; it += 256) {
    int d = it & (DIc - 1);
    int p = it >> 7;
    int w = w0 + p;
    float acc = 0.f;
#pragma unroll
    for (int kh = 0; kh < 3; kh++) {
      int hh = h + kh - 1;
      if ((unsigned)hh < 48u) {
#pragma unroll
        for (int kw = 0; kw < 3; kw++) {
          int wp = w + kw - 1;
          if ((unsigned)wp < 48u)
            acc += conv_w[((branch * DIc + d) * 3 + kh) * 3 + kw] *
                   xcpre[(hh * 48 + wp) * DIc + d];
        }
      }
    }
    float v = acc + conv_b[branch * DIc + d];
    float s = v * sigmoidf(v);
    xv[p][d] = s;
    xact[(h * 48 + w) * DIc + d] = s;
  }
  __syncthreads();
  // phase 1: 144 projection rows (k,r) x 4 pixels, 128-dot each
  if (tid < Kc * 36) {
    int k = tid / 36, r = tid % 36;
    float acc[4] = {0.f, 0.f, 0.f, 0.f};
    const float* wrow = xp_w + ((branch * Kc + k) * 36 + r) * DIc;
    for (int cc = 0; cc < DIc; cc++) {
      float wvv = wrow[cc];
#pragma unroll
      for (int p = 0; p < 4; p++) acc[p] += wvv * xv[p][cc];
    }
#pragma unroll
    for (int p = 0; p < 4; p++) {
      int w = w0 + p;
      int lr = h * 48 + w, lcx = w * 48 + h;
      int pos = (k == 0) ? lr : (k == 1) ? lcx : (k == 2) ? (Lc - 1 - lr) : (Lc - 1 - lcx);
      if (r < Rc) dts[p][k][r] = acc[p];
      else if (r < Rc + Sc) Bsb[(k * Lc + pos) * Sc + (r - Rc)] = acc[p];
      else Csb[(k * Lc + pos) * Sc + (r - Rc - Sc)] = acc[p];
    }
  }
  __syncthreads();
  // phase 2: dt = softplus(dt_w @ dts + dt_b)  (4 px x 4 k x 128 d)
  for (int it = tid; it < 4 * Kc * DIc; it += 256) {
    int d = it & (DIc - 1);
    int k = (it >> 7) & 3;
    int p = it >> 9;
    const float* dwr = dt_w + ((branch * Kc + k) * DIc + d) * Rc;
    float v = dt_b[(branch * Kc + k) * DIc + d];
#pragma unroll
    for (int r = 0; r < Rc; r++) v += dwr[r] * dts[p][k][r];
    float sp = (v > 20.f) ? v : __logf(1.f + __expf(v));
    int w = w0 + p;
    int lr = h * 48 + w, lcx = w * 48 + h;
    int pos = (k == 0) ? lr : (k == 1) ? lcx : (k == 2) ? (Lc - 1 - lr) : (Lc - 1 - lcx);
    dtg[(k * Lc + pos) * DIc + d] = sp;
  }
}

// scan-position -> row-major pixel index, per direction
DEV int perm_idx(int k, int l) {
  if (k == 0) return l;
  if (k == 1) return (l % 48) * 48 + l / 48;
  if (k == 2) return Lc - 1 - l;
  int pp = Lc - 1 - l;
  return (pp % 48) * 48 + pp / 48;
}

// ---------------------------------------------------------------------------
// scan pass 1: per-chunk summaries (prod dA, chunk scan with h=0)
// thread = (chunk,k,d); grid.x = 96, block = 256
__global__ __launch_bounds__(256) void k_scan1(const float* A_logs, int branch, float* ws) {
  int gid = blockIdx.x * 256 + threadIdx.x;
  const float* dtg = ws + OFF_DT;
  const float* xact = ws + OFF_XACT;
  const float* Bsb = ws + OFF_BS;
  float* sumA = ws + OFF_SUMA;
  float* sumB = ws + OFF_SUMB;
  int d = gid & (DIc - 1);
  int k = (gid >> 7) & 3;
  int ch = gid >> 9;
  float A[Sc];
  const float* ap = A_logs + ((branch * Kc + k) * DIc + d) * Sc;
#pragma unroll
  for (int s = 0; s < Sc; s++) A[s] = -__expf(ap[s]);
  float pA[Sc], aB[Sc];
#pragma unroll
  for (int s = 0; s < Sc; s++) { pA[s] = 1.f; aB[s] = 0.f; }
  int l0 = ch * CHL;
  for (int i = 0; i < CHL; i++) {
    int l = l0 + i;
    int idx = perm_idx(k, l);
    float dtv = dtg[(k * Lc + l) * DIc + d];
    float xvv = xact[idx * DIc + d];
    float dtx = dtv * xvv;
    const float* Bf = Bsb + (k * Lc + l) * Sc;
#pragma unroll
    for (int s = 0; s < Sc; s++) {
      float da = __expf(dtv * A[s]);
      pA[s] *= da;
      aB[s] = da * aB[s] + dtx * Bf[s];
    }
  }
  float* sa = sumA + ((k * NCH + ch) * DIc + d) * Sc;
  float* sb = sumB + ((k * NCH + ch) * DIc + d) * Sc;
#pragma unroll
  for (int s = 0; s < Sc; s++) { sa[s] = pA[s]; sb[s] = aB[s]; }
}

// ---------------------------------------------------------------------------
// scan pass 2: in-thread prefix combine over earlier chunks, then rescan chunk
// and emit y = h·C + D*x. Same mapping as pass 1.
__global__ __launch_bounds__(256) void k_scan2(const float* A_logs, const float* Ds,
                                               int branch, float* ws) {
  int gid = blockIdx.x * 256 + threadIdx.x;
  const float* dtg = ws + OFF_DT;
  const float* xact = ws + OFF_XACT;
  const float* Bsb = ws + OFF_BS;
  const float* Csb = ws + OFF_CS;
  const float* sumA = ws + OFF_SUMA;
  const float* sumB = ws + OFF_SUMB;
  float* yb = ws + OFF_Y;
  int d = gid & (DIc - 1);
  int k = (gid >> 7) & 3;
  int ch = gid >> 9;
  float A[Sc];
  const float* ap = A_logs + ((branch * Kc + k) * DIc + d) * Sc;
#pragma unroll
  for (int s = 0; s < Sc; s++) A[s] = -__expf(ap[s]);
  float h[Sc];
#pragma unroll
  for (int s = 0; s < Sc; s++) h[s] = 0.f;
  for (int c2 = 0; c2 < ch; c2++) {
    const float* af = sumA + ((k * NCH + c2) * DIc + d) * Sc;
    const float* bf = sumB + ((k * NCH + c2) * DIc + d) * Sc;
#pragma unroll
    for (int s = 0; s < Sc; s++) h[s] = af[s] * h[s] + bf[s];
  }
  float Dv = Ds[(branch * Kc + k) * DIc + d];
  int l0 = ch * CHL;
  for (int i = 0; i < CHL; i++) {
    int l = l0 + i;
    int idx = perm_idx(k, l);
    float dtv = dtg[(k * Lc + l) * DIc + d];
    float xvv = xact[idx * DIc + d];
    float dtx = dtv * xvv;
    const float* Bf = Bsb + (k * Lc + l) * Sc;
    const float* Cf = Csb + (k * Lc + l) * Sc;
    float acc = 0.f;
#pragma unroll
    for (int s = 0; s < Sc; s++) {
      float da = __expf(dtv * A[s]);
      h[s] = da * h[s] + dtx * Bf[s];
      acc += h[s] * Cf[s];
    }
    yb[(k * Lc + l) * DIc + d] = acc + Dv * xvv;
  }
}

// ---------------------------------------------------------------------------
// combine 4 directions + LN over DI + *silu(z) + out-proj; mode 0 -> bias[targ],
// mode 1 -> cur update (+ optional final fp32 output write)
// block = 256, 4 pixels per block, grid.x = 576
__global__ __launch_bounds__(256) void k_out(const float* onw, const float* onb,
                                             const float* ow, const float* ob,
                                             int branch, int mode, int targ, int finalw,
                                             const float* curb, float* nxtb, float* outp,
                                             float* ws) {
  __shared__ float yy[4][DIc];
  __shared__ float ml[4][DIc];
  __shared__ float mnv[4], isv[4];
  int tid = threadIdx.x;
  const float* yb = ws + OFF_Y;
  const float* zb = ws + OFF_Z;
  float* biasb = ws + OFF_BIAS;
  int l0 = blockIdx.x * 4;
  for (int it = tid; it < 4 * DIc; it += 256) {
    int d = it & (DIc - 1), p = it >> 7;
    int l = l0 + p;
    int hh = l / 48, www = l % 48;
    int lr = l, lcx = www * 48 + hh;
    float v = yb[(0 * Lc + lr) * DIc + d] + yb[(1 * Lc + lcx) * DIc + d] +
              yb[(2 * Lc + (Lc - 1 - lr)) * DIc + d] +
              yb[(3 * Lc + (Lc - 1 - lcx)) * DIc + d];
    yy[p][d] = v;
  }
  __syncthreads();
  {
    int wv = tid >> 6, c = tid & 63;
    float a = yy[wv][c], b = yy[wv][c + 64];
    float s1 = wsum(a + b);
    float s2 = wsum(a * a + b * b);
    float mu = s1 * (1.f / 128.f);
    float var = s2 * (1.f / 128.f) - mu * mu;
    if (c == 0) { mnv[wv] = mu; isv[wv] = rsqrtf(var + 1e-6f); }
  }
  __syncthreads();
  for (int it = tid; it < 4 * DIc; it += 256) {
    int d = it & (DIc - 1), p = it >> 7;
    int l = l0 + p;
    float m = (yy[p][d] - mnv[p]) * isv[p] * onw[branch * DIc + d] + onb[branch * DIc + d];
    float zv = zb[l * DIc + d];
    ml[p][d] = m * zv * sigmoidf(zv);
  }
  __syncthreads();
  {
    int p = tid >> 6, c = tid & 63;
    int l = l0 + p;
    const float* owr = ow + (branch * Cc + c) * DIc;
    float acc = ob[branch * Cc + c];
    for (int d2 = 0; d2 < DIc; d2++) acc += owr[d2] * ml[p][d2];
    if (mode == 0) {
      biasb[(targ * Lc + l) * Cc + c] = acc;
    } else {
      float cv = curb[l * Cc + c];
      float nv = cv * __expf(acc) + biasb[(targ * Lc + l) * Cc + c];
      nxtb[l * Cc + c] = nv;
      if (finalw) {
        // diagnostic sentinel: clamp non-finite to 12345 so a NaN upstream is
        // distinguishable from a dtype/layout mismatch in the bench report.
        outp[c * Lc + l] = isfinite(nv) ? nv : 12345.0f;
      }
    }
  }
}

// ---------------------------------------------------------------------------
extern "C" void kernel_launch(void* const* d_in, const int* in_sizes, int n_in,
                              void* d_out, int out_size, void* d_ws, size_t ws_size,
                              hipStream_t stream) {
  (void)in_sizes; (void)n_in; (void)out_size; (void)ws_size;
  const float* img    = (const float*)d_in[0];
  const float* dz     = (const float*)d_in[1];
  const float* sigma  = (const float*)d_in[2];
  const float* in_w   = (const float*)d_in[3];
  const float* in_b   = (const float*)d_in[4];
  const float* conv_w = (const float*)d_in[5];
  const float* conv_b = (const float*)d_in[6];
  const float* xp_w   = (const float*)d_in[7];
  const float* dt_w   = (const float*)d_in[8];
  const float* dt_b   = (const float*)d_in[9];
  const float* A_logs = (const float*)d_in[10];
  const float* Ds     = (const float*)d_in[11];
  const float* onw    = (const float*)d_in[12];
  const float* onb    = (const float*)d_in[13];
  const float* ow     = (const float*)d_in[14];
  const float* ob     = (const float*)d_in[15];
  const float* niw    = (const float*)d_in[16];
  const float* nib    = (const float*)d_in[17];
  const float* ndw    = (const float*)d_in[18];
  const float* ndb    = (const float*)d_in[19];
  float* ws = (float*)d_ws;
  float* outp = (float*)d_out;

  hipLaunchKernelGGL(k_prep, dim3(576), dim3(256), 0, stream, dz, sigma, ndw, ndb, ws);

  // bias branch: 4 timesteps, sequential, reusing the single slot
  for (int t = 0; t < Tc; t++) {
    hipLaunchKernelGGL(k_inproj, dim3(288), dim3(256), 0, stream, img, niw, nib,
                       (const float*)nullptr, (const float*)nullptr, in_w, in_b, 1, 0, t, ws);
    hipLaunchKernelGGL(k_conv_proj, dim3(576), dim3(256), 0, stream, conv_w, conv_b,
                       xp_w, dt_w, dt_b, 1, ws);
    hipLaunchKernelGGL(k_scan1, dim3(96), dim3(256), 0, stream, A_logs, 1, ws);
    hipLaunchKernelGGL(k_scan2, dim3(96), dim3(256), 0, stream, A_logs, Ds, 1, ws);
    hipLaunchKernelGGL(k_out, dim3(576), dim3(256), 0, stream, onw, onb, ow, ob, 1, 0, t,
                       0, (const float*)nullptr, (float*)nullptr, (float*)nullptr, ws);
  }

  // sequential s-branch, rotating state buffers
  float* b[3] = {ws + OFF_B0, ws + OFF_B1, ws + OFF_B2};
  for (int t = 0; t < Tc; t++) {
    float* prevb = b[t % 3];
    float* curb  = b[(t + 1) % 3];
    float* nxtb  = b[(t + 2) % 3];
    hipLaunchKernelGGL(k_inproj, dim3(288), dim3(256), 0, stream, img, niw, nib,
                       (const float*)curb, (const float*)prevb, in_w, in_b, 0, 1, 0, ws);
    hipLaunchKernelGGL(k_conv_proj, dim3(576), dim3(256), 0, stream, conv_w, conv_b,
                       xp_w, dt_w, dt_b, 0, ws);
    hipLaunchKernelGGL(k_scan1, dim3(96), dim3(256), 0, stream, A_logs, 0, ws);
    hipLaunchKernelGGL(k_scan2, dim3(96), dim3(256), 0, stream, A_logs, Ds, 0, ws);
    hipLaunchKernelGGL(k_out, dim3(576), dim3(256), 0, stream, onw, onb, ow, ob, 0, 1,
                       t, (t == Tc - 1) ? 1 : 0, (const float*)curb, nxtb, outp, ws);
  }
}

// Round 4
// 861.897 us; speedup vs baseline: 1.2375x; 1.2375x over previous
//
#include <hip/hip_runtime.h>
#include <hip/hip_bf16.h>

#define DEV __device__ __forceinline__

// Problem constants
constexpr int Cc = 64, DIc = 128, Sc = 16, Rc = 4, Kc = 4;
constexpr int Hh = 48, Ww = 48, Lc = 2304, Tc = 4;
constexpr int NCH = 96, CHL = 24;   // 96 chunks of length 24 (96*24 = 2304)

// Workspace layout (float offsets). ONE slot, reused by all 8 SS2D rounds.
// Total 5,787,648 floats = 23.2 MB.
constexpr int OFF_XCPRE = 0;              // L*DI  [l][d]  xz first half (pre-conv)
constexpr int OFF_Z     = 294912;         // L*DI  [l][d]
constexpr int OFF_XACT  = 589824;         // L*DI  [l][d]  conv+silu output
constexpr int OFF_DTS   = 884736;         // K*R*L [k][r][pos]  (scan-position indexed)
constexpr int OFF_BS    = 921600;         // K*L*S [k][pos][s]
constexpr int OFF_CS    = 1069056;        // K*L*S
constexpr int OFF_Y     = 1216512;        // K*L*DI [k][pos][d]
constexpr int OFF_SUMA  = 2396160;        // K*NCH*DI*S [k][ch][d][s]
constexpr int OFF_SUMB  = 3182592;        // K*NCH*DI*S
constexpr int OFF_H0    = 3969024;        // K*NCH*DI*S  per-chunk initial state
constexpr int OFF_B0    = 4755456;        // L*C state buffers [l][c]
constexpr int OFF_B1    = 4902912;
constexpr int OFF_B2    = 5050368;
constexpr int OFF_BIAS  = 5197824;        // T*L*C [t][l][c]

DEV float wsum(float v) {
#pragma unroll
  for (int m = 32; m; m >>= 1) v += __shfl_xor(v, m, 64);
  return v;
}
DEV float wmax(float v) {
#pragma unroll
  for (int m = 32; m; m >>= 1) v = fmaxf(v, __shfl_xor(v, m, 64));
  return v;
}
DEV float sigmoidf(float x) { return 1.f / (1.f + __expf(-x)); }

// ---------------------------------------------------------------------------
// prep: prev = LN_c(difficult_zone); cur = prev * exp(sigma)
__global__ __launch_bounds__(256) void k_prep(const float* dz, const float* sigma,
                                              const float* ndw, const float* ndb,
                                              float* ws) {
  int tid = threadIdx.x;
  int wv = tid >> 6, c = tid & 63;
  int l = blockIdx.x * 4 + wv;
  float* prevb = ws + OFF_B0;
  float* curb  = ws + OFF_B1;
  float v = dz[c * Lc + l];
  float mu = wsum(v) * (1.f / 64.f);
  float var = wsum(v * v) * (1.f / 64.f) - mu * mu;
  float pv = (v - mu) * rsqrtf(var + 1e-6f) * ndw[c] + ndb[c];
  prevb[l * Cc + c] = pv;
  curb[l * Cc + c] = pv * __expf(sigma[c * Lc + l]);
}

// ---------------------------------------------------------------------------
// input projection: x -> xz = in_w @ x + in_b, split into xcpre / z.
// mode 0: x = LN_c(image_sequence[tstep]); mode 1: x = KL(cur, prev)
__global__ __launch_bounds__(256) void k_inproj(const float* img, const float* niw,
                                                const float* nib, const float* curb,
                                                const float* prevb, const float* in_w,
                                                const float* in_b, int branch, int mode,
                                                int tstep, float* ws) {
  __shared__ float xv[8][64];
  int tid = threadIdx.x;
  float* xcpre = ws + OFF_XCPRE;
  float* zbuf  = ws + OFF_Z;
  int l0 = blockIdx.x * 8;
  int wv = tid >> 6, c = tid & 63;
#pragma unroll
  for (int q = 0; q < 2; q++) {
    int p = wv * 2 + q;
    int l = l0 + p;
    float x;
    if (mode == 0) {
      float v = img[(tstep * Cc + c) * Lc + l];
      float mu = wsum(v) * (1.f / 64.f);
      float var = wsum(v * v) * (1.f / 64.f) - mu * mu;
      x = (v - mu) * rsqrtf(var + 1e-6f) * niw[c] + nib[c];
    } else {
      float pv = prevb[l * Cc + c], cv = curb[l * Cc + c];
      float mp = wmax(pv);
      float sp = wsum(__expf(pv - mp));
      float lp = pv - mp - __logf(sp);
      float mq = wmax(cv);
      float sq = wsum(__expf(cv - mq));
      float lq = cv - mq - __logf(sq);
      x = __expf(lp) * (lp - lq);
    }
    xv[p][c] = x;
  }
  __syncthreads();
  int d = tid;  // 0..255 output rows
  float acc[8];
#pragma unroll
  for (int p = 0; p < 8; p++) acc[p] = 0.f;
  const float* wrow = in_w + (branch * 2 * DIc + d) * Cc;
  for (int cc = 0; cc < Cc; cc++) {
    float wval = wrow[cc];
#pragma unroll
    for (int p = 0; p < 8; p++) acc[p] += wval * xv[p][cc];
  }
  float bv = in_b[branch * 2 * DIc + d];
  if (d < DIc) {
#pragma unroll
    for (int p = 0; p < 8; p++) xcpre[(l0 + p) * DIc + d] = acc[p] + bv;
  } else {
    int dd = d - DIc;
#pragma unroll
    for (int p = 0; p < 8; p++) zbuf[(l0 + p) * DIc + dd] = acc[p] + bv;
  }
}

// ---------------------------------------------------------------------------
// depthwise conv3x3 + silu -> xact; xp proj -> dts/Bs/Cs (dt computed in scans)
__global__ __launch_bounds__(256) void k_conv_proj(const float* conv_w, const float* conv_b,
                                                   const float* xp_w, int branch, float* ws) {
  __shared__ float xv[4][DIc];
  int tid = threadIdx.x;
  float* xcpre = ws + OFF_XCPRE;
  float* xact  = ws + OFF_XACT;
  float* dtsb  = ws + OFF_DTS;
  float* Bsb   = ws + OFF_BS;
  float* Csb   = ws + OFF_CS;
  int h = blockIdx.x / 12;
  int w0 = (blockIdx.x % 12) * 4;
  // phase 0: conv + silu (4 px x 128 ch)
  for (int it = tid; it < 4 * DIc; it += 256) {
    int d = it & (DIc - 1);
    int p = it >> 7;
    int w = w0 + p;
    float acc = 0.f;
#pragma unroll
    for (int kh = 0; kh < 3; kh++) {
      int hh = h + kh - 1;
      if ((unsigned)hh < 48u) {
#pragma unroll
        for (int kw = 0; kw < 3; kw++) {
          int wp = w + kw - 1;
          if ((unsigned)wp < 48u)
            acc += conv_w[((branch * DIc + d) * 3 + kh) * 3 + kw] *
                   xcpre[(hh * 48 + wp) * DIc + d];
        }
      }
    }
    float v = acc + conv_b[branch * DIc + d];
    float s = v * sigmoidf(v);
    xv[p][d] = s;
    xact[(h * 48 + w) * DIc + d] = s;
  }
  __syncthreads();
  // phase 1: 144 projection rows (k,r) x 4 pixels, 128-dot each
  if (tid < Kc * 36) {
    int k = tid / 36, r = tid % 36;
    float acc[4] = {0.f, 0.f, 0.f, 0.f};
    const float* wrow = xp_w + ((branch * Kc + k) * 36 + r) * DIc;
    for (int cc = 0; cc < DIc; cc++) {
      float wvv = wrow[cc];
#pragma unroll
      for (int p = 0; p < 4; p++) acc[p] += wvv * xv[p][cc];
    }
#pragma unroll
    for (int p = 0; p < 4; p++) {
      int w = w0 + p;
      int lr = h * 48 + w, lcx = w * 48 + h;
      int pos = (k == 0) ? lr : (k == 1) ? lcx : (k == 2) ? (Lc - 1 - lr) : (Lc - 1 - lcx);
      if (r < Rc) dtsb[(k * Rc + r) * Lc + pos] = acc[p];
      else if (r < Rc + Sc) Bsb[(k * Lc + pos) * Sc + (r - Rc)] = acc[p];
      else Csb[(k * Lc + pos) * Sc + (r - Rc - Sc)] = acc[p];
    }
  }
}

// scan-position -> row-major pixel index, per direction
DEV int perm_idx(int k, int l) {
  if (k == 0) return l;
  if (k == 1) return (l % 48) * 48 + l / 48;
  if (k == 2) return Lc - 1 - l;
  int pp = Lc - 1 - l;
  return (pp % 48) * 48 + pp / 48;
}

DEV float softplusf(float v) { return (v > 20.f) ? v : __logf(1.f + __expf(v)); }

// ---------------------------------------------------------------------------
// scan pass 1: per-chunk summaries (prod dA, chunk scan with h=0).
// thread = (ch,k,d); grid.x = K*NCH*DI/256 = 192, dt computed on the fly.
__global__ __launch_bounds__(256) void k_scan1(const float* A_logs, const float* dt_w,
                                               const float* dt_b, int branch, float* ws) {
  int gid = blockIdx.x * 256 + threadIdx.x;
  const float* xact = ws + OFF_XACT;
  const float* Bsb  = ws + OFF_BS;
  const float* dtsb = ws + OFF_DTS;
  float* sumA = ws + OFF_SUMA;
  float* sumB = ws + OFF_SUMB;
  int d = gid & (DIc - 1);
  int k = (gid >> 7) & 3;
  int ch = gid >> 9;
  float A[Sc];
  const float* ap = A_logs + ((branch * Kc + k) * DIc + d) * Sc;
#pragma unroll
  for (int s = 0; s < Sc; s++) A[s] = -__expf(ap[s]);
  float dw[Rc];
  const float* dwr = dt_w + ((branch * Kc + k) * DIc + d) * Rc;
#pragma unroll
  for (int r = 0; r < Rc; r++) dw[r] = dwr[r];
  float db = dt_b[(branch * Kc + k) * DIc + d];
  float pA[Sc], aB[Sc];
#pragma unroll
  for (int s = 0; s < Sc; s++) { pA[s] = 1.f; aB[s] = 0.f; }
  int l0 = ch * CHL;
  for (int i = 0; i < CHL; i++) {
    int l = l0 + i;
    float v = db;
#pragma unroll
    for (int r = 0; r < Rc; r++) v += dw[r] * dtsb[(k * Rc + r) * Lc + l];
    float dtv = softplusf(v);
    int idx = perm_idx(k, l);
    float xvv = xact[idx * DIc + d];
    float dtx = dtv * xvv;
    const float* Bf = Bsb + (k * Lc + l) * Sc;
#pragma unroll
    for (int s = 0; s < Sc; s++) {
      float da = __expf(dtv * A[s]);
      pA[s] *= da;
      aB[s] = da * aB[s] + dtx * Bf[s];
    }
  }
  float* sa = sumA + ((k * NCH + ch) * DIc + d) * Sc;
  float* sb = sumB + ((k * NCH + ch) * DIc + d) * Sc;
#pragma unroll
  for (int s = 0; s < Sc; s++) { sa[s] = pA[s]; sb[s] = aB[s]; }
}

// ---------------------------------------------------------------------------
// scan mid: sequential combine over chunk summaries -> per-chunk initial state.
// thread = (k,d,s); grid.x = K*DI*S/256 = 32
__global__ __launch_bounds__(256) void k_scan_mid(float* ws) {
  int gid = blockIdx.x * 256 + threadIdx.x;
  const float* sumA = ws + OFF_SUMA;
  const float* sumB = ws + OFF_SUMB;
  float* h0 = ws + OFF_H0;
  int s = gid & (Sc - 1);
  int d = (gid >> 4) & (DIc - 1);
  int k = gid >> 11;
  float h = 0.f;
  for (int ch = 0; ch < NCH; ch++) {
    int base = ((k * NCH + ch) * DIc + d) * Sc + s;
    h0[base] = h;
    h = sumA[base] * h + sumB[base];
  }
}

// ---------------------------------------------------------------------------
// scan pass 2: load h0, rescan chunk, emit y = h·C + D*x.
__global__ __launch_bounds__(256) void k_scan2(const float* A_logs, const float* dt_w,
                                               const float* dt_b, const float* Ds,
                                               int branch, float* ws) {
  int gid = blockIdx.x * 256 + threadIdx.x;
  const float* xact = ws + OFF_XACT;
  const float* Bsb  = ws + OFF_BS;
  const float* Csb  = ws + OFF_CS;
  const float* dtsb = ws + OFF_DTS;
  const float* h0b  = ws + OFF_H0;
  float* yb = ws + OFF_Y;
  int d = gid & (DIc - 1);
  int k = (gid >> 7) & 3;
  int ch = gid >> 9;
  float A[Sc];
  const float* ap = A_logs + ((branch * Kc + k) * DIc + d) * Sc;
#pragma unroll
  for (int s = 0; s < Sc; s++) A[s] = -__expf(ap[s]);
  float dw[Rc];
  const float* dwr = dt_w + ((branch * Kc + k) * DIc + d) * Rc;
#pragma unroll
  for (int r = 0; r < Rc; r++) dw[r] = dwr[r];
  float db = dt_b[(branch * Kc + k) * DIc + d];
  float h[Sc];
  const float* hp = h0b + ((k * NCH + ch) * DIc + d) * Sc;
#pragma unroll
  for (int s = 0; s < Sc; s++) h[s] = hp[s];
  float Dv = Ds[(branch * Kc + k) * DIc + d];
  int l0 = ch * CHL;
  for (int i = 0; i < CHL; i++) {
    int l = l0 + i;
    float v = db;
#pragma unroll
    for (int r = 0; r < Rc; r++) v += dw[r] * dtsb[(k * Rc + r) * Lc + l];
    float dtv = softplusf(v);
    int idx = perm_idx(k, l);
    float xvv = xact[idx * DIc + d];
    float dtx = dtv * xvv;
    const float* Bf = Bsb + (k * Lc + l) * Sc;
    const float* Cf = Csb + (k * Lc + l) * Sc;
    float acc = 0.f;
#pragma unroll
    for (int s = 0; s < Sc; s++) {
      float da = __expf(dtv * A[s]);
      h[s] = da * h[s] + dtx * Bf[s];
      acc += h[s] * Cf[s];
    }
    yb[(k * Lc + l) * DIc + d] = acc + Dv * xvv;
  }
}

// ---------------------------------------------------------------------------
// combine 4 directions + LN over DI + *silu(z) + out-proj; mode 0 -> bias[targ],
// mode 1 -> cur update (+ optional final fp32 output write)
__global__ __launch_bounds__(256) void k_out(const float* onw, const float* onb,
                                             const float* ow, const float* ob,
                                             int branch, int mode, int targ, int finalw,
                                             const float* curb, float* nxtb, float* outp,
                                             float* ws) {
  __shared__ float yy[4][DIc];
  __shared__ float ml[4][DIc];
  __shared__ float mnv[4], isv[4];
  int tid = threadIdx.x;
  const float* yb = ws + OFF_Y;
  const float* zb = ws + OFF_Z;
  float* biasb = ws + OFF_BIAS;
  int l0 = blockIdx.x * 4;
  for (int it = tid; it < 4 * DIc; it += 256) {
    int d = it & (DIc - 1), p = it >> 7;
    int l = l0 + p;
    int hh = l / 48, www = l % 48;
    int lr = l, lcx = www * 48 + hh;
    float v = yb[(0 * Lc + lr) * DIc + d] + yb[(1 * Lc + lcx) * DIc + d] +
              yb[(2 * Lc + (Lc - 1 - lr)) * DIc + d] +
              yb[(3 * Lc + (Lc - 1 - lcx)) * DIc + d];
    yy[p][d] = v;
  }
  __syncthreads();
  {
    int wv = tid >> 6, c = tid & 63;
    float a = yy[wv][c], b = yy[wv][c + 64];
    float s1 = wsum(a + b);
    float s2 = wsum(a * a + b * b);
    float mu = s1 * (1.f / 128.f);
    float var = s2 * (1.f / 128.f) - mu * mu;
    if (c == 0) { mnv[wv] = mu; isv[wv] = rsqrtf(var + 1e-6f); }
  }
  __syncthreads();
  for (int it = tid; it < 4 * DIc; it += 256) {
    int d = it & (DIc - 1), p = it >> 7;
    int l = l0 + p;
    float m = (yy[p][d] - mnv[p]) * isv[p] * onw[branch * DIc + d] + onb[branch * DIc + d];
    float zv = zb[l * DIc + d];
    ml[p][d] = m * zv * sigmoidf(zv);
  }
  __syncthreads();
  {
    int p = tid >> 6, c = tid & 63;
    int l = l0 + p;
    const float* owr = ow + (branch * Cc + c) * DIc;
    float acc = ob[branch * Cc + c];
    for (int d2 = 0; d2 < DIc; d2++) acc += owr[d2] * ml[p][d2];
    if (mode == 0) {
      biasb[(targ * Lc + l) * Cc + c] = acc;
    } else {
      float cv = curb[l * Cc + c];
      float nv = cv * __expf(acc) + biasb[(targ * Lc + l) * Cc + c];
      nxtb[l * Cc + c] = nv;
      if (finalw) outp[c * Lc + l] = nv;
    }
  }
}

// ---------------------------------------------------------------------------
extern "C" void kernel_launch(void* const* d_in, const int* in_sizes, int n_in,
                              void* d_out, int out_size, void* d_ws, size_t ws_size,
                              hipStream_t stream) {
  (void)in_sizes; (void)n_in; (void)out_size; (void)ws_size;
  const float* img    = (const float*)d_in[0];
  const float* dz     = (const float*)d_in[1];
  const float* sigma  = (const float*)d_in[2];
  const float* in_w   = (const float*)d_in[3];
  const float* in_b   = (const float*)d_in[4];
  const float* conv_w = (const float*)d_in[5];
  const float* conv_b = (const float*)d_in[6];
  const float* xp_w   = (const float*)d_in[7];
  const float* dt_w   = (const float*)d_in[8];
  const float* dt_b   = (const float*)d_in[9];
  const float* A_logs = (const float*)d_in[10];
  const float* Ds     = (const float*)d_in[11];
  const float* onw    = (const float*)d_in[12];
  const float* onb    = (const float*)d_in[13];
  const float* ow     = (const float*)d_in[14];
  const float* ob     = (const float*)d_in[15];
  const float* niw    = (const float*)d_in[16];
  const float* nib    = (const float*)d_in[17];
  const float* ndw    = (const float*)d_in[18];
  const float* ndb    = (const float*)d_in[19];
  float* ws = (float*)d_ws;
  float* outp = (float*)d_out;

  hipLaunchKernelGGL(k_prep, dim3(576), dim3(256), 0, stream, dz, sigma, ndw, ndb, ws);

  // bias branch: 4 timesteps, sequential, reusing the single slot
  for (int t = 0; t < Tc; t++) {
    hipLaunchKernelGGL(k_inproj, dim3(288), dim3(256), 0, stream, img, niw, nib,
                       (const float*)nullptr, (const float*)nullptr, in_w, in_b, 1, 0, t, ws);
    hipLaunchKernelGGL(k_conv_proj, dim3(576), dim3(256), 0, stream, conv_w, conv_b,
                       xp_w, 1, ws);
    hipLaunchKernelGGL(k_scan1, dim3(192), dim3(256), 0, stream, A_logs, dt_w, dt_b, 1, ws);
    hipLaunchKernelGGL(k_scan_mid, dim3(32), dim3(256), 0, stream, ws);
    hipLaunchKernelGGL(k_scan2, dim3(192), dim3(256), 0, stream, A_logs, dt_w, dt_b, Ds, 1, ws);
    hipLaunchKernelGGL(k_out, dim3(576), dim3(256), 0, stream, onw, onb, ow, ob, 1, 0, t,
                       0, (const float*)nullptr, (float*)nullptr, (float*)nullptr, ws);
  }

  // sequential s-branch, rotating state buffers
  float* b[3] = {ws + OFF_B0, ws + OFF_B1, ws + OFF_B2};
  for (int t = 0; t < Tc; t++) {
    float* prevb = b[t % 3];
    float* curb  = b[(t + 1) % 3];
    float* nxtb  = b[(t + 2) % 3];
    hipLaunchKernelGGL(k_inproj, dim3(288), dim3(256), 0, stream, img, niw, nib,
                       (const float*)curb, (const float*)prevb, in_w, in_b, 0, 1, 0, ws);
    hipLaunchKernelGGL(k_conv_proj, dim3(576), dim3(256), 0, stream, conv_w, conv_b,
                       xp_w, 0, ws);
    hipLaunchKernelGGL(k_scan1, dim3(192), dim3(256), 0, stream, A_logs, dt_w, dt_b, 0, ws);
    hipLaunchKernelGGL(k_scan_mid, dim3(32), dim3(256), 0, stream, ws);
    hipLaunchKernelGGL(k_scan2, dim3(192), dim3(256), 0, stream, A_logs, dt_w, dt_b, Ds, 0, ws);
    hipLaunchKernelGGL(k_out, dim3(576), dim3(256), 0, stream, onw, onb, ow, ob, 0, 1,
                       t, (t == Tc - 1) ? 1 : 0, (const float*)curb, nxtb, outp, ws);
  }
}

// Round 5
// 622.615 us; speedup vs baseline: 1.7131x; 1.3843x over previous
//
#include <hip/hip_runtime.h>
#include <hip/hip_bf16.h>

#define DEV __device__ __forceinline__

// Problem constants
constexpr int Cc = 64, DIc = 128, Sc = 16, Rc = 4, Kc = 4;
constexpr int Hh = 48, Ww = 48, Lc = 2304, Tc = 4;
constexpr int NCH = 144, CHL = 16;   // 144 chunks of length 16 (144*16 = 2304)

// Workspace layout (float offsets). 5 slots: 0-3 = bias branch t=0..3, 4 = s-branch.
// Per-slot 5,935,104 floats; total ~123 MB (ws_size = 268 MB, verified via fill counters).
constexpr int OFF_XCPRE = 0;              // L*DI  [l][d]  xz first half (pre-conv)
constexpr int OFF_Z     = 294912;         // L*DI  [l][d]
constexpr int OFF_XACT  = 589824;         // L*DI  [l][d]  conv+silu output
constexpr int OFF_DTS   = 884736;         // K*R*L [k][r][pos]  (scan-position indexed)
constexpr int OFF_BS    = 921600;         // K*L*S [k][pos][s]
constexpr int OFF_CS    = 1069056;        // K*L*S
constexpr int OFF_Y     = 1216512;        // K*L*DI [k][pos][d]
constexpr int OFF_SUMA  = 2396160;        // K*NCH*DI*S [k][ch][d][s]
constexpr int OFF_SUMB  = 3575808;        // K*NCH*DI*S
constexpr int OFF_H0    = 4755456;        // K*NCH*DI*S  per-chunk initial state
constexpr int SLOTF     = 5935104;
constexpr int OFF_B0    = 5 * SLOTF;      // L*C state buffers [l][c]
constexpr int OFF_B1    = OFF_B0 + Lc * Cc;
constexpr int OFF_B2    = OFF_B1 + Lc * Cc;
constexpr int OFF_BIAS  = OFF_B2 + Lc * Cc;       // T*L*C [t][l][c]

DEV float wsum(float v) {
#pragma unroll
  for (int m = 32; m; m >>= 1) v += __shfl_xor(v, m, 64);
  return v;
}
DEV float wmax(float v) {
#pragma unroll
  for (int m = 32; m; m >>= 1) v = fmaxf(v, __shfl_xor(v, m, 64));
  return v;
}
DEV float sigmoidf(float x) { return 1.f / (1.f + __expf(-x)); }
DEV float softplusf(float v) { return (v > 20.f) ? v : __logf(1.f + __expf(v)); }

// ---------------------------------------------------------------------------
// prep: prev = LN_c(difficult_zone); cur = prev * exp(sigma)
__global__ __launch_bounds__(256) void k_prep(const float* dz, const float* sigma,
                                              const float* ndw, const float* ndb,
                                              float* ws) {
  int tid = threadIdx.x;
  int wv = tid >> 6, c = tid & 63;
  int l = blockIdx.x * 4 + wv;
  float* prevb = ws + OFF_B0;
  float* curb  = ws + OFF_B1;
  float v = dz[c * Lc + l];
  float mu = wsum(v) * (1.f / 64.f);
  float var = wsum(v * v) * (1.f / 64.f) - mu * mu;
  float pv = (v - mu) * rsqrtf(var + 1e-6f) * ndw[c] + ndb[c];
  prevb[l * Cc + c] = pv;
  curb[l * Cc + c] = pv * __expf(sigma[c * Lc + l]);
}

// ---------------------------------------------------------------------------
// mega input projection, grid (288, 5). slot 0-3: x = LN_c(img[slot]) (branch 1);
// slot 4: x = KL(cur_0, prev_0) (branch 0). 8 pixels per block.
__global__ __launch_bounds__(256) void k_inproj(const float* img, const float* niw,
                                                const float* nib, const float* in_w,
                                                const float* in_b, float* ws) {
  __shared__ float xv[8][64];
  int tid = threadIdx.x;
  int slot = blockIdx.y;
  int branch = (slot >= 4) ? 0 : 1;
  float* base = ws + (size_t)slot * SLOTF;
  float* xcpre = base + OFF_XCPRE;
  float* zbuf  = base + OFF_Z;
  const float* prevb = ws + OFF_B0;
  const float* curb  = ws + OFF_B1;
  int l0 = blockIdx.x * 8;
  int wv = tid >> 6, c = tid & 63;
#pragma unroll
  for (int q = 0; q < 2; q++) {
    int p = wv * 2 + q;
    int l = l0 + p;
    float x;
    if (branch == 1) {
      float v = img[(slot * Cc + c) * Lc + l];
      float mu = wsum(v) * (1.f / 64.f);
      float var = wsum(v * v) * (1.f / 64.f) - mu * mu;
      x = (v - mu) * rsqrtf(var + 1e-6f) * niw[c] + nib[c];
    } else {
      float pv = prevb[l * Cc + c], cv = curb[l * Cc + c];
      float mp = wmax(pv);
      float sp = wsum(__expf(pv - mp));
      float lp = pv - mp - __logf(sp);
      float mq = wmax(cv);
      float sq = wsum(__expf(cv - mq));
      float lq = cv - mq - __logf(sq);
      x = __expf(lp) * (lp - lq);
    }
    xv[p][c] = x;
  }
  __syncthreads();
  int d = tid;  // 0..255 output rows
  float acc[8];
#pragma unroll
  for (int p = 0; p < 8; p++) acc[p] = 0.f;
  const float* wrow = in_w + (branch * 2 * DIc + d) * Cc;
  for (int cc = 0; cc < Cc; cc++) {
    float wval = wrow[cc];
#pragma unroll
    for (int p = 0; p < 8; p++) acc[p] += wval * xv[p][cc];
  }
  float bv = in_b[branch * 2 * DIc + d];
  if (d < DIc) {
#pragma unroll
    for (int p = 0; p < 8; p++) xcpre[(l0 + p) * DIc + d] = acc[p] + bv;
  } else {
    int dd = d - DIc;
#pragma unroll
    for (int p = 0; p < 8; p++) zbuf[(l0 + p) * DIc + dd] = acc[p] + bv;
  }
}

// ---------------------------------------------------------------------------
// depthwise conv3x3 + silu -> xact; xp proj -> dts/Bs/Cs. grid (576, nslots).
__global__ __launch_bounds__(256) void k_conv_proj(const float* conv_w, const float* conv_b,
                                                   const float* xp_w, int slot_base,
                                                   float* ws) {
  __shared__ float xv[4][DIc];
  int tid = threadIdx.x;
  int slot = slot_base + blockIdx.y;
  int branch = (slot >= 4) ? 0 : 1;
  float* base = ws + (size_t)slot * SLOTF;
  float* xcpre = base + OFF_XCPRE;
  float* xact  = base + OFF_XACT;
  float* dtsb  = base + OFF_DTS;
  float* Bsb   = base + OFF_BS;
  float* Csb   = base + OFF_CS;
  int h = blockIdx.x / 12;
  int w0 = (blockIdx.x % 12) * 4;
  // phase 0: conv + silu (4 px x 128 ch)
  for (int it = tid; it < 4 * DIc; it += 256) {
    int d = it & (DIc - 1);
    int p = it >> 7;
    int w = w0 + p;
    float acc = 0.f;
#pragma unroll
    for (int kh = 0; kh < 3; kh++) {
      int hh = h + kh - 1;
      if ((unsigned)hh < 48u) {
#pragma unroll
        for (int kw = 0; kw < 3; kw++) {
          int wp = w + kw - 1;
          if ((unsigned)wp < 48u)
            acc += conv_w[((branch * DIc + d) * 3 + kh) * 3 + kw] *
                   xcpre[(hh * 48 + wp) * DIc + d];
        }
      }
    }
    float v = acc + conv_b[branch * DIc + d];
    float s = v * sigmoidf(v);
    xv[p][d] = s;
    xact[(h * 48 + w) * DIc + d] = s;
  }
  __syncthreads();
  // phase 1: 144 projection rows (k,r) x 4 pixels, 128-dot each
  if (tid < Kc * 36) {
    int k = tid / 36, r = tid % 36;
    float acc[4] = {0.f, 0.f, 0.f, 0.f};
    const float* wrow = xp_w + ((branch * Kc + k) * 36 + r) * DIc;
    for (int cc = 0; cc < DIc; cc++) {
      float wvv = wrow[cc];
#pragma unroll
      for (int p = 0; p < 4; p++) acc[p] += wvv * xv[p][cc];
    }
#pragma unroll
    for (int p = 0; p < 4; p++) {
      int w = w0 + p;
      int lr = h * 48 + w, lcx = w * 48 + h;
      int pos = (k == 0) ? lr : (k == 1) ? lcx : (k == 2) ? (Lc - 1 - lr) : (Lc - 1 - lcx);
      if (r < Rc) dtsb[(k * Rc + r) * Lc + pos] = acc[p];
      else if (r < Rc + Sc) Bsb[(k * Lc + pos) * Sc + (r - Rc)] = acc[p];
      else Csb[(k * Lc + pos) * Sc + (r - Rc - Sc)] = acc[p];
    }
  }
}

// scan-position -> row-major pixel index, per direction
DEV int perm_idx(int k, int l) {
  if (k == 0) return l;
  if (k == 1) return (l % 48) * 48 + l / 48;
  if (k == 2) return Lc - 1 - l;
  int pp = Lc - 1 - l;
  return (pp % 48) * 48 + pp / 48;
}

// ---------------------------------------------------------------------------
// scan pass 1: per-chunk summaries. thread = (ch,k,d); grid (288, nslots).
__global__ __launch_bounds__(256) void k_scan1(const float* A_logs, const float* dt_w,
                                               const float* dt_b, int slot_base, float* ws) {
  int gid = blockIdx.x * 256 + threadIdx.x;
  int slot = slot_base + blockIdx.y;
  int branch = (slot >= 4) ? 0 : 1;
  float* base = ws + (size_t)slot * SLOTF;
  const float* xact = base + OFF_XACT;
  const float* Bsb  = base + OFF_BS;
  const float* dtsb = base + OFF_DTS;
  float* sumA = base + OFF_SUMA;
  float* sumB = base + OFF_SUMB;
  int d = gid & (DIc - 1);
  int k = (gid >> 7) & 3;
  int ch = gid >> 9;
  float A[Sc];
  const float* ap = A_logs + ((branch * Kc + k) * DIc + d) * Sc;
#pragma unroll
  for (int s = 0; s < Sc; s++) A[s] = -__expf(ap[s]);
  float dw[Rc];
  const float* dwr = dt_w + ((branch * Kc + k) * DIc + d) * Rc;
#pragma unroll
  for (int r = 0; r < Rc; r++) dw[r] = dwr[r];
  float db = dt_b[(branch * Kc + k) * DIc + d];
  float pA[Sc], aB[Sc];
#pragma unroll
  for (int s = 0; s < Sc; s++) { pA[s] = 1.f; aB[s] = 0.f; }
  int l0 = ch * CHL;
  for (int i = 0; i < CHL; i++) {
    int l = l0 + i;
    float v = db;
#pragma unroll
    for (int r = 0; r < Rc; r++) v += dw[r] * dtsb[(k * Rc + r) * Lc + l];
    float dtv = softplusf(v);
    int idx = perm_idx(k, l);
    float xvv = xact[idx * DIc + d];
    float dtx = dtv * xvv;
    const float* Bf = Bsb + (k * Lc + l) * Sc;
#pragma unroll
    for (int s = 0; s < Sc; s++) {
      float da = __expf(dtv * A[s]);
      pA[s] *= da;
      aB[s] = da * aB[s] + dtx * Bf[s];
    }
  }
  float* sa = sumA + ((k * NCH + ch) * DIc + d) * Sc;
  float* sb = sumB + ((k * NCH + ch) * DIc + d) * Sc;
#pragma unroll
  for (int s = 0; s < Sc; s++) { sa[s] = pA[s]; sb[s] = aB[s]; }
}

// ---------------------------------------------------------------------------
// scan mid: sequential combine over chunk summaries -> per-chunk initial state.
// thread = (k,d,s); grid (32, nslots).
__global__ __launch_bounds__(256) void k_scan_mid(int slot_base, float* ws) {
  int gid = blockIdx.x * 256 + threadIdx.x;
  int slot = slot_base + blockIdx.y;
  float* base = ws + (size_t)slot * SLOTF;
  const float* sumA = base + OFF_SUMA;
  const float* sumB = base + OFF_SUMB;
  float* h0 = base + OFF_H0;
  int s = gid & (Sc - 1);
  int d = (gid >> 4) & (DIc - 1);
  int k = gid >> 11;
  float h = 0.f;
  for (int ch = 0; ch < NCH; ch++) {
    int idx = ((k * NCH + ch) * DIc + d) * Sc + s;
    h0[idx] = h;
    h = sumA[idx] * h + sumB[idx];
  }
}

// ---------------------------------------------------------------------------
// scan pass 2: load h0, rescan chunk, emit y = h·C + D*x. grid (288, nslots).
__global__ __launch_bounds__(256) void k_scan2(const float* A_logs, const float* dt_w,
                                               const float* dt_b, const float* Ds,
                                               int slot_base, float* ws) {
  int gid = blockIdx.x * 256 + threadIdx.x;
  int slot = slot_base + blockIdx.y;
  int branch = (slot >= 4) ? 0 : 1;
  float* base = ws + (size_t)slot * SLOTF;
  const float* xact = base + OFF_XACT;
  const float* Bsb  = base + OFF_BS;
  const float* Csb  = base + OFF_CS;
  const float* dtsb = base + OFF_DTS;
  const float* h0b  = base + OFF_H0;
  float* yb = base + OFF_Y;
  int d = gid & (DIc - 1);
  int k = (gid >> 7) & 3;
  int ch = gid >> 9;
  float A[Sc];
  const float* ap = A_logs + ((branch * Kc + k) * DIc + d) * Sc;
#pragma unroll
  for (int s = 0; s < Sc; s++) A[s] = -__expf(ap[s]);
  float dw[Rc];
  const float* dwr = dt_w + ((branch * Kc + k) * DIc + d) * Rc;
#pragma unroll
  for (int r = 0; r < Rc; r++) dw[r] = dwr[r];
  float db = dt_b[(branch * Kc + k) * DIc + d];
  float h[Sc];
  const float* hp = h0b + ((k * NCH + ch) * DIc + d) * Sc;
#pragma unroll
  for (int s = 0; s < Sc; s++) h[s] = hp[s];
  float Dv = Ds[(branch * Kc + k) * DIc + d];
  int l0 = ch * CHL;
  for (int i = 0; i < CHL; i++) {
    int l = l0 + i;
    float v = db;
#pragma unroll
    for (int r = 0; r < Rc; r++) v += dw[r] * dtsb[(k * Rc + r) * Lc + l];
    float dtv = softplusf(v);
    int idx = perm_idx(k, l);
    float xvv = xact[idx * DIc + d];
    float dtx = dtv * xvv;
    const float* Bf = Bsb + (k * Lc + l) * Sc;
    const float* Cf = Csb + (k * Lc + l) * Sc;
    float acc = 0.f;
#pragma unroll
    for (int s = 0; s < Sc; s++) {
      float da = __expf(dtv * A[s]);
      h[s] = da * h[s] + dtx * Bf[s];
      acc += h[s] * Cf[s];
    }
    yb[(k * Lc + l) * DIc + d] = acc + Dv * xvv;
  }
}

// ---------------------------------------------------------------------------
// bias-branch epilogue: combine dirs + LN + silu(z) + out-proj -> biasb[slot].
// grid (576, 4), slots 0-3, branch 1.
__global__ __launch_bounds__(256) void k_out_bias(const float* onw, const float* onb,
                                                  const float* ow, const float* ob,
                                                  float* ws) {
  __shared__ float yy[4][DIc];
  __shared__ float ml[4][DIc];
  __shared__ float mnv[4], isv[4];
  int tid = threadIdx.x;
  int slot = blockIdx.y;
  float* base = ws + (size_t)slot * SLOTF;
  const float* yb = base + OFF_Y;
  const float* zb = base + OFF_Z;
  float* biasb = ws + OFF_BIAS;
  int l0 = blockIdx.x * 4;
  for (int it = tid; it < 4 * DIc; it += 256) {
    int d = it & (DIc - 1), p = it >> 7;
    int l = l0 + p;
    int hh = l / 48, www = l % 48;
    int lr = l, lcx = www * 48 + hh;
    float v = yb[(0 * Lc + lr) * DIc + d] + yb[(1 * Lc + lcx) * DIc + d] +
              yb[(2 * Lc + (Lc - 1 - lr)) * DIc + d] +
              yb[(3 * Lc + (Lc - 1 - lcx)) * DIc + d];
    yy[p][d] = v;
  }
  __syncthreads();
  {
    int wv = tid >> 6, c = tid & 63;
    float a = yy[wv][c], b = yy[wv][c + 64];
    float s1 = wsum(a + b);
    float s2 = wsum(a * a + b * b);
    float mu = s1 * (1.f / 128.f);
    float var = s2 * (1.f / 128.f) - mu * mu;
    if (c == 0) { mnv[wv] = mu; isv[wv] = rsqrtf(var + 1e-6f); }
  }
  __syncthreads();
  for (int it = tid; it < 4 * DIc; it += 256) {
    int d = it & (DIc - 1), p = it >> 7;
    int l = l0 + p;
    float m = (yy[p][d] - mnv[p]) * isv[p] * onw[DIc + d] + onb[DIc + d];  // branch 1
    float zv = zb[l * DIc + d];
    ml[p][d] = m * zv * sigmoidf(zv);
  }
  __syncthreads();
  {
    int p = tid >> 6, c = tid & 63;
    int l = l0 + p;
    const float* owr = ow + (Cc + c) * DIc;  // branch 1
    float acc = ob[Cc + c];
    for (int d2 = 0; d2 < DIc; d2++) acc += owr[d2] * ml[p][d2];
    biasb[(slot * Lc + l) * Cc + c] = acc;
  }
}

// ---------------------------------------------------------------------------
// s-branch epilogue (slot 4, branch 0): combine + LN + silu(z) + out-proj,
// state update cur' = cur*exp(s) + bias[targ]; if fuse: KL(cur',cur) + in-proj
// for the NEXT round (writes slot-4 xcpre/z); if finalw: write d_out.
// grid (576).
__global__ __launch_bounds__(256) void k_out_s(const float* onw, const float* onb,
                                               const float* ow, const float* ob,
                                               const float* in_w, const float* in_b,
                                               int targ, int fuse, int finalw,
                                               const float* curb, float* nxtb,
                                               float* outp, float* ws) {
  __shared__ float yy[4][DIc];
  __shared__ float ml[4][DIc];
  __shared__ float xv[4][64];
  __shared__ float mnv[4], isv[4];
  int tid = threadIdx.x;
  float* base = ws + (size_t)4 * SLOTF;
  const float* yb = base + OFF_Y;
  const float* zb = base + OFF_Z;
  float* xcpre = base + OFF_XCPRE;
  float* zbuf  = base + OFF_Z;
  const float* biasb = ws + OFF_BIAS;
  int l0 = blockIdx.x * 4;
  for (int it = tid; it < 4 * DIc; it += 256) {
    int d = it & (DIc - 1), p = it >> 7;
    int l = l0 + p;
    int hh = l / 48, www = l % 48;
    int lr = l, lcx = www * 48 + hh;
    float v = yb[(0 * Lc + lr) * DIc + d] + yb[(1 * Lc + lcx) * DIc + d] +
              yb[(2 * Lc + (Lc - 1 - lr)) * DIc + d] +
              yb[(3 * Lc + (Lc - 1 - lcx)) * DIc + d];
    yy[p][d] = v;
  }
  __syncthreads();
  {
    int wv = tid >> 6, c = tid & 63;
    float a = yy[wv][c], b = yy[wv][c + 64];
    float s1 = wsum(a + b);
    float s2 = wsum(a * a + b * b);
    float mu = s1 * (1.f / 128.f);
    float var = s2 * (1.f / 128.f) - mu * mu;
    if (c == 0) { mnv[wv] = mu; isv[wv] = rsqrtf(var + 1e-6f); }
  }
  __syncthreads();
  for (int it = tid; it < 4 * DIc; it += 256) {
    int d = it & (DIc - 1), p = it >> 7;
    int l = l0 + p;
    float m = (yy[p][d] - mnv[p]) * isv[p] * onw[d] + onb[d];  // branch 0
    float zv = zb[l * DIc + d];
    ml[p][d] = m * zv * sigmoidf(zv);
  }
  __syncthreads();
  // out-proj + state update; wave p = pixel, lane c = channel
  {
    int p = tid >> 6, c = tid & 63;
    int l = l0 + p;
    const float* owr = ow + c * DIc;  // branch 0
    float acc = ob[c];
    for (int d2 = 0; d2 < DIc; d2++) acc += owr[d2] * ml[p][d2];
    float cv = curb[l * Cc + c];
    float nv = cv * __expf(acc) + biasb[(targ * Lc + l) * Cc + c];
    nxtb[l * Cc + c] = nv;
    if (finalw) outp[c * Lc + l] = nv;
    if (fuse) {
      // KL(cur_{t+1}=nv, prev_{t+1}=cv) — wave-local softmax over 64 channels
      float mp = wmax(cv);
      float sp = wsum(__expf(cv - mp));
      float lp = cv - mp - __logf(sp);
      float mq = wmax(nv);
      float sq = wsum(__expf(nv - mq));
      float lq = nv - mq - __logf(sq);
      xv[p][c] = __expf(lp) * (lp - lq);
    }
  }
  if (fuse) {
    __syncthreads();
    // in-proj for next round: 256 rows x 4 pixels (branch 0)
    int d = tid;
    float acc[4] = {0.f, 0.f, 0.f, 0.f};
    const float* wrow = in_w + d * Cc;
    for (int cc = 0; cc < Cc; cc++) {
      float wval = wrow[cc];
#pragma unroll
      for (int p = 0; p < 4; p++) acc[p] += wval * xv[p][cc];
    }
    float bv = in_b[d];
    if (d < DIc) {
#pragma unroll
      for (int p = 0; p < 4; p++) xcpre[(l0 + p) * DIc + d] = acc[p] + bv;
    } else {
      int dd = d - DIc;
#pragma unroll
      for (int p = 0; p < 4; p++) zbuf[(l0 + p) * DIc + dd] = acc[p] + bv;
    }
  }
}

// ---------------------------------------------------------------------------
extern "C" void kernel_launch(void* const* d_in, const int* in_sizes, int n_in,
                              void* d_out, int out_size, void* d_ws, size_t ws_size,
                              hipStream_t stream) {
  (void)in_sizes; (void)n_in; (void)out_size; (void)ws_size;
  const float* img    = (const float*)d_in[0];
  const float* dz     = (const float*)d_in[1];
  const float* sigma  = (const float*)d_in[2];
  const float* in_w   = (const float*)d_in[3];
  const float* in_b   = (const float*)d_in[4];
  const float* conv_w = (const float*)d_in[5];
  const float* conv_b = (const float*)d_in[6];
  const float* xp_w   = (const float*)d_in[7];
  const float* dt_w   = (const float*)d_in[8];
  const float* dt_b   = (const float*)d_in[9];
  const float* A_logs = (const float*)d_in[10];
  const float* Ds     = (const float*)d_in[11];
  const float* onw    = (const float*)d_in[12];
  const float* onb    = (const float*)d_in[13];
  const float* ow     = (const float*)d_in[14];
  const float* ob     = (const float*)d_in[15];
  const float* niw    = (const float*)d_in[16];
  const float* nib    = (const float*)d_in[17];
  const float* ndw    = (const float*)d_in[18];
  const float* ndb    = (const float*)d_in[19];
  float* ws = (float*)d_ws;
  float* outp = (float*)d_out;

  hipLaunchKernelGGL(k_prep, dim3(576), dim3(256), 0, stream, dz, sigma, ndw, ndb, ws);

  // mega round: bias t=0..3 (slots 0-3) + s-branch t=0 (slot 4)
  hipLaunchKernelGGL(k_inproj, dim3(288, 5), dim3(256), 0, stream, img, niw, nib,
                     in_w, in_b, ws);
  hipLaunchKernelGGL(k_conv_proj, dim3(576, 5), dim3(256), 0, stream, conv_w, conv_b,
                     xp_w, 0, ws);
  hipLaunchKernelGGL(k_scan1, dim3(288, 5), dim3(256), 0, stream, A_logs, dt_w, dt_b, 0, ws);
  hipLaunchKernelGGL(k_scan_mid, dim3(32, 5), dim3(256), 0, stream, 0, ws);
  hipLaunchKernelGGL(k_scan2, dim3(288, 5), dim3(256), 0, stream, A_logs, dt_w, dt_b, Ds,
                     0, ws);
  hipLaunchKernelGGL(k_out_bias, dim3(576, 4), dim3(256), 0, stream, onw, onb, ow, ob, ws);

  // s-branch rounds; cur state alternates B1 <-> B2. k_out_s(t) fuses next inproj.
  float* b1 = ws + OFF_B1;
  float* b2 = ws + OFF_B2;
  hipLaunchKernelGGL(k_out_s, dim3(576), dim3(256), 0, stream, onw, onb, ow, ob,
                     in_w, in_b, 0, 1, 0, (const float*)b1, b2, outp, ws);
  for (int t = 1; t < Tc; t++) {
    const float* curb = (t & 1) ? b2 : b1;
    float* nxtb       = (t & 1) ? b1 : b2;
    hipLaunchKernelGGL(k_conv_proj, dim3(576, 1), dim3(256), 0, stream, conv_w, conv_b,
                       xp_w, 4, ws);
    hipLaunchKernelGGL(k_scan1, dim3(288, 1), dim3(256), 0, stream, A_logs, dt_w, dt_b,
                       4, ws);
    hipLaunchKernelGGL(k_scan_mid, dim3(32, 1), dim3(256), 0, stream, 4, ws);
    hipLaunchKernelGGL(k_scan2, dim3(288, 1), dim3(256), 0, stream, A_logs, dt_w, dt_b, Ds,
                       4, ws);
    hipLaunchKernelGGL(k_out_s, dim3(576), dim3(256), 0, stream, onw, onb, ow, ob,
                       in_w, in_b, t, (t == Tc - 1) ? 0 : 1, (t == Tc - 1) ? 1 : 0,
                       curb, nxtb, outp, ws);
  }
}

// Round 6
// 516.498 us; speedup vs baseline: 2.0651x; 1.2055x over previous
//
#include <hip/hip_runtime.h>
#include <hip/hip_bf16.h>

#define DEV __device__ __forceinline__

// Problem constants
constexpr int Cc = 64, DIc = 128, Sc = 16, Rc = 4, Kc = 4;
constexpr int Hh = 48, Ww = 48, Lc = 2304, Tc = 4;
constexpr int NCH = 144, CHL = 16;   // 144 chunks of length 16

// Workspace layout (float offsets). 5 slots: 0-3 = bias branch t=0..3, 4 = s-branch.
constexpr int OFF_XCPRE = 0;              // L*DI  [l][d]
constexpr int OFF_Z     = 294912;         // L*DI  [l][d]
constexpr int OFF_XACT  = 589824;         // L*DI  [l][d]
constexpr int OFF_DTS   = 884736;         // K*R*L [k][r][pos]
constexpr int OFF_BS    = 921600;         // K*L*S [k][pos][s]
constexpr int OFF_CS    = 1069056;        // K*L*S
constexpr int OFF_Y     = 1216512;        // K*L*DI [k][pos][d]
constexpr int OFF_SUMA  = 2396160;        // K*NCH*DI*S
constexpr int OFF_SUMB  = 3575808;
constexpr int OFF_H0    = 4755456;
constexpr int SLOTF     = 5935104;
constexpr int OFF_B0    = 5 * SLOTF;      // L*C state buffers [l][c]
constexpr int OFF_B1    = OFF_B0 + Lc * Cc;
constexpr int OFF_B2    = OFF_B1 + Lc * Cc;
constexpr int OFF_BIAS  = OFF_B2 + Lc * Cc;       // T*L*C [t][l][c]
// Lane-major transposed weights (one-time k_transpose):
constexpr int OFF_TW    = OFF_BIAS + Tc * Lc * Cc;
constexpr int TW_INW  = 0;        // [2][64][256]  inwT[(b*64+cc)*256 + row]
constexpr int TW_XPW  = 32768;    // [2][128][144] xpwT[(b*128+cc)*144 + kr]
constexpr int TW_OW   = 69632;    // [2][128][64]  owT[(b*128+d)*64 + c]
constexpr int TW_CW   = 86016;    // [2][9][128]   cwT[(b*9+kk)*128 + d]
constexpr int TW_AT   = 88320;    // [2][4][16][128] AT[((bk)*16+s)*128 + d]
constexpr int TW_DTW  = 104704;   // [2][4][4][128]  dtwT[((bk)*4+r)*128 + d]

DEV float wsum(float v) {
#pragma unroll
  for (int m = 32; m; m >>= 1) v += __shfl_xor(v, m, 64);
  return v;
}
DEV float wmax(float v) {
#pragma unroll
  for (int m = 32; m; m >>= 1) v = fmaxf(v, __shfl_xor(v, m, 64));
  return v;
}
DEV float sigmoidf(float x) { return 1.f / (1.f + __expf(-x)); }
DEV float softplusf(float v) { return (v > 20.f) ? v : __logf(1.f + __expf(v)); }

// ---------------------------------------------------------------------------
// one-time: transpose weights into lane-major layouts (coalesced writes).
__global__ __launch_bounds__(256) void k_transpose(const float* in_w, const float* xp_w,
                                                   const float* ow, const float* conv_w,
                                                   const float* A_logs, const float* dt_w,
                                                   float* tw) {
  int i = blockIdx.x * 256 + threadIdx.x;
  if (i < 32768) {  // inwT
    int d = i & 255, cc = (i >> 8) & 63, b = i >> 14;
    tw[TW_INW + i] = in_w[(b * 256 + d) * 64 + cc];
  }
  if (i < 36864) {  // xpwT
    int kr = i % 144, cc = (i / 144) & 127, b = i / (144 * 128);
    tw[TW_XPW + i] = xp_w[(b * 144 + kr) * 128 + cc];
  }
  if (i < 16384) {  // owT
    int c = i & 63, d = (i >> 6) & 127, b = i >> 13;
    tw[TW_OW + i] = ow[(b * 64 + c) * 128 + d];
  }
  if (i < 2304) {   // cwT
    int d = i & 127, kk = (i >> 7) % 9, b = i / 1152;
    tw[TW_CW + i] = conv_w[(b * 128 + d) * 9 + kk];
  }
  if (i < 16384) {  // AT
    int d = i & 127, bks = i >> 7;
    int s = bks & 15, bk = bks >> 4;
    tw[TW_AT + i] = A_logs[(bk * 128 + d) * 16 + s];
  }
  if (i < 4096) {   // dtwT
    int d = i & 127, bkr = i >> 7;
    int r = bkr & 3, bk = bkr >> 2;
    tw[TW_DTW + i] = dt_w[(bk * 128 + d) * 4 + r];
  }
}

// ---------------------------------------------------------------------------
// prep: prev = LN_c(difficult_zone); cur = prev * exp(sigma)
__global__ __launch_bounds__(256) void k_prep(const float* dz, const float* sigma,
                                              const float* ndw, const float* ndb,
                                              float* ws) {
  int tid = threadIdx.x;
  int wv = tid >> 6, c = tid & 63;
  int l = blockIdx.x * 4 + wv;
  float* prevb = ws + OFF_B0;
  float* curb  = ws + OFF_B1;
  float v = dz[c * Lc + l];
  float mu = wsum(v) * (1.f / 64.f);
  float var = wsum(v * v) * (1.f / 64.f) - mu * mu;
  float pv = (v - mu) * rsqrtf(var + 1e-6f) * ndw[c] + ndb[c];
  prevb[l * Cc + c] = pv;
  curb[l * Cc + c] = pv * __expf(sigma[c * Lc + l]);
}

// ---------------------------------------------------------------------------
// mega input projection, grid (288, 5). slot 0-3: x = LN_c(img[slot]) (branch 1);
// slot 4: x = KL(cur_0, prev_0) (branch 0). 8 pixels per block.
__global__ __launch_bounds__(256) void k_inproj(const float* img, const float* niw,
                                                const float* nib, const float* in_b,
                                                float* ws) {
  __shared__ float xv[8][64];
  int tid = threadIdx.x;
  int slot = blockIdx.y;
  int branch = (slot >= 4) ? 0 : 1;
  float* base = ws + (size_t)slot * SLOTF;
  float* xcpre = base + OFF_XCPRE;
  float* zbuf  = base + OFF_Z;
  const float* prevb = ws + OFF_B0;
  const float* curb  = ws + OFF_B1;
  const float* wT = ws + OFF_TW + TW_INW + branch * 64 * 256;
  int l0 = blockIdx.x * 8;
  int wv = tid >> 6, c = tid & 63;
#pragma unroll
  for (int q = 0; q < 2; q++) {
    int p = wv * 2 + q;
    int l = l0 + p;
    float x;
    if (branch == 1) {
      float v = img[(slot * Cc + c) * Lc + l];
      float mu = wsum(v) * (1.f / 64.f);
      float var = wsum(v * v) * (1.f / 64.f) - mu * mu;
      x = (v - mu) * rsqrtf(var + 1e-6f) * niw[c] + nib[c];
    } else {
      float pv = prevb[l * Cc + c], cv = curb[l * Cc + c];
      float mp = wmax(pv);
      float sp = wsum(__expf(pv - mp));
      float lp = pv - mp - __logf(sp);
      float mq = wmax(cv);
      float sq = wsum(__expf(cv - mq));
      float lq = cv - mq - __logf(sq);
      x = __expf(lp) * (lp - lq);
    }
    xv[p][c] = x;
  }
  __syncthreads();
  int d = tid;  // 0..255 output rows
  float acc[8];
#pragma unroll
  for (int p = 0; p < 8; p++) acc[p] = 0.f;
  for (int cc = 0; cc < Cc; cc++) {
    float wval = wT[cc * 256 + d];  // lane-major: coalesced
#pragma unroll
    for (int p = 0; p < 8; p++) acc[p] += wval * xv[p][cc];
  }
  float bv = in_b[branch * 2 * DIc + d];
  if (d < DIc) {
#pragma unroll
    for (int p = 0; p < 8; p++) xcpre[(l0 + p) * DIc + d] = acc[p] + bv;
  } else {
    int dd = d - DIc;
#pragma unroll
    for (int p = 0; p < 8; p++) zbuf[(l0 + p) * DIc + dd] = acc[p] + bv;
  }
}

// ---------------------------------------------------------------------------
// depthwise conv3x3 + silu -> xact; xp proj -> dts/Bs/Cs. grid (576, nslots).
__global__ __launch_bounds__(256) void k_conv_proj(const float* conv_b, int slot_base,
                                                   float* ws) {
  __shared__ float xv[4][DIc];
  int tid = threadIdx.x;
  int slot = slot_base + blockIdx.y;
  int branch = (slot >= 4) ? 0 : 1;
  float* base = ws + (size_t)slot * SLOTF;
  float* xcpre = base + OFF_XCPRE;
  float* xact  = base + OFF_XACT;
  float* dtsb  = base + OFF_DTS;
  float* Bsb   = base + OFF_BS;
  float* Csb   = base + OFF_CS;
  const float* cwT = ws + OFF_TW + TW_CW + branch * 9 * 128;
  const float* xpwT = ws + OFF_TW + TW_XPW + branch * 128 * 144;
  int h = blockIdx.x / 12;
  int w0 = (blockIdx.x % 12) * 4;
  // phase 0: conv + silu (4 px x 128 ch)
  for (int it = tid; it < 4 * DIc; it += 256) {
    int d = it & (DIc - 1);
    int p = it >> 7;
    int w = w0 + p;
    float acc = 0.f;
#pragma unroll
    for (int kh = 0; kh < 3; kh++) {
      int hh = h + kh - 1;
      if ((unsigned)hh < 48u) {
#pragma unroll
        for (int kw = 0; kw < 3; kw++) {
          int wp = w + kw - 1;
          if ((unsigned)wp < 48u)
            acc += cwT[(kh * 3 + kw) * 128 + d] * xcpre[(hh * 48 + wp) * DIc + d];
        }
      }
    }
    float v = acc + conv_b[branch * DIc + d];
    float s = v * sigmoidf(v);
    xv[p][d] = s;
    xact[(h * 48 + w) * DIc + d] = s;
  }
  __syncthreads();
  // phase 1: 144 projection rows (k,r) x 4 pixels; kr == tid so xpwT is coalesced
  if (tid < Kc * 36) {
    int k = tid / 36, r = tid % 36;
    float acc[4] = {0.f, 0.f, 0.f, 0.f};
    for (int cc = 0; cc < DIc; cc++) {
      float wvv = xpwT[cc * 144 + tid];
#pragma unroll
      for (int p = 0; p < 4; p++) acc[p] += wvv * xv[p][cc];
    }
#pragma unroll
    for (int p = 0; p < 4; p++) {
      int w = w0 + p;
      int lr = h * 48 + w, lcx = w * 48 + h;
      int pos = (k == 0) ? lr : (k == 1) ? lcx : (k == 2) ? (Lc - 1 - lr) : (Lc - 1 - lcx);
      if (r < Rc) dtsb[(k * Rc + r) * Lc + pos] = acc[p];
      else if (r < Rc + Sc) Bsb[(k * Lc + pos) * Sc + (r - Rc)] = acc[p];
      else Csb[(k * Lc + pos) * Sc + (r - Rc - Sc)] = acc[p];
    }
  }
}

// scan-position -> row-major pixel index, per direction
DEV int perm_idx(int k, int l) {
  if (k == 0) return l;
  if (k == 1) return (l % 48) * 48 + l / 48;
  if (k == 2) return Lc - 1 - l;
  int pp = Lc - 1 - l;
  return (pp % 48) * 48 + pp / 48;
}

// ---------------------------------------------------------------------------
// scan pass 1: per-chunk summaries. thread = (ch,k,d); grid (288, nslots).
__global__ __launch_bounds__(256) void k_scan1(const float* dt_b, int slot_base, float* ws) {
  int gid = blockIdx.x * 256 + threadIdx.x;
  int slot = slot_base + blockIdx.y;
  int branch = (slot >= 4) ? 0 : 1;
  float* base = ws + (size_t)slot * SLOTF;
  const float* xact = base + OFF_XACT;
  const float* Bsb  = base + OFF_BS;
  const float* dtsb = base + OFF_DTS;
  float* sumA = base + OFF_SUMA;
  float* sumB = base + OFF_SUMB;
  int d = gid & (DIc - 1);
  int k = (gid >> 7) & 3;
  int ch = gid >> 9;
  int bk = branch * Kc + k;
  const float* AT   = ws + OFF_TW + TW_AT;
  const float* dtwT = ws + OFF_TW + TW_DTW;
  float A[Sc];
#pragma unroll
  for (int s = 0; s < Sc; s++) A[s] = -__expf(AT[(bk * 16 + s) * 128 + d]);
  float dw[Rc];
#pragma unroll
  for (int r = 0; r < Rc; r++) dw[r] = dtwT[(bk * 4 + r) * 128 + d];
  float db = dt_b[bk * DIc + d];
  float pA[Sc], aB[Sc];
#pragma unroll
  for (int s = 0; s < Sc; s++) { pA[s] = 1.f; aB[s] = 0.f; }
  int l0 = ch * CHL;
  for (int i = 0; i < CHL; i++) {
    int l = l0 + i;
    float v = db;
#pragma unroll
    for (int r = 0; r < Rc; r++) v += dw[r] * dtsb[(k * Rc + r) * Lc + l];
    float dtv = softplusf(v);
    int idx = perm_idx(k, l);
    float xvv = xact[idx * DIc + d];
    float dtx = dtv * xvv;
    const float* Bf = Bsb + (k * Lc + l) * Sc;
#pragma unroll
    for (int s = 0; s < Sc; s++) {
      float da = __expf(dtv * A[s]);
      pA[s] *= da;
      aB[s] = da * aB[s] + dtx * Bf[s];
    }
  }
  float* sa = sumA + ((k * NCH + ch) * DIc + d) * Sc;
  float* sb = sumB + ((k * NCH + ch) * DIc + d) * Sc;
#pragma unroll
  for (int s = 0; s < Sc; s++) { sa[s] = pA[s]; sb[s] = aB[s]; }
}

// ---------------------------------------------------------------------------
// scan mid: sequential combine over chunk summaries -> per-chunk initial state.
__global__ __launch_bounds__(256) void k_scan_mid(int slot_base, float* ws) {
  int gid = blockIdx.x * 256 + threadIdx.x;
  int slot = slot_base + blockIdx.y;
  float* base = ws + (size_t)slot * SLOTF;
  const float* sumA = base + OFF_SUMA;
  const float* sumB = base + OFF_SUMB;
  float* h0 = base + OFF_H0;
  int s = gid & (Sc - 1);
  int d = (gid >> 4) & (DIc - 1);
  int k = gid >> 11;
  float h = 0.f;
  for (int ch = 0; ch < NCH; ch++) {
    int idx = ((k * NCH + ch) * DIc + d) * Sc + s;
    h0[idx] = h;
    h = sumA[idx] * h + sumB[idx];
  }
}

// ---------------------------------------------------------------------------
// scan pass 2: load h0, rescan chunk, emit y = h·C + D*x. grid (288, nslots).
__global__ __launch_bounds__(256) void k_scan2(const float* dt_b, const float* Ds,
                                               int slot_base, float* ws) {
  int gid = blockIdx.x * 256 + threadIdx.x;
  int slot = slot_base + blockIdx.y;
  int branch = (slot >= 4) ? 0 : 1;
  float* base = ws + (size_t)slot * SLOTF;
  const float* xact = base + OFF_XACT;
  const float* Bsb  = base + OFF_BS;
  const float* Csb  = base + OFF_CS;
  const float* dtsb = base + OFF_DTS;
  const float* h0b  = base + OFF_H0;
  float* yb = base + OFF_Y;
  int d = gid & (DIc - 1);
  int k = (gid >> 7) & 3;
  int ch = gid >> 9;
  int bk = branch * Kc + k;
  const float* AT   = ws + OFF_TW + TW_AT;
  const float* dtwT = ws + OFF_TW + TW_DTW;
  float A[Sc];
#pragma unroll
  for (int s = 0; s < Sc; s++) A[s] = -__expf(AT[(bk * 16 + s) * 128 + d]);
  float dw[Rc];
#pragma unroll
  for (int r = 0; r < Rc; r++) dw[r] = dtwT[(bk * 4 + r) * 128 + d];
  float db = dt_b[bk * DIc + d];
  float h[Sc];
  const float* hp = h0b + ((k * NCH + ch) * DIc + d) * Sc;
#pragma unroll
  for (int s = 0; s < Sc; s++) h[s] = hp[s];
  float Dv = Ds[bk * DIc + d];
  int l0 = ch * CHL;
  for (int i = 0; i < CHL; i++) {
    int l = l0 + i;
    float v = db;
#pragma unroll
    for (int r = 0; r < Rc; r++) v += dw[r] * dtsb[(k * Rc + r) * Lc + l];
    float dtv = softplusf(v);
    int idx = perm_idx(k, l);
    float xvv = xact[idx * DIc + d];
    float dtx = dtv * xvv;
    const float* Bf = Bsb + (k * Lc + l) * Sc;
    const float* Cf = Csb + (k * Lc + l) * Sc;
    float acc = 0.f;
#pragma unroll
    for (int s = 0; s < Sc; s++) {
      float da = __expf(dtv * A[s]);
      h[s] = da * h[s] + dtx * Bf[s];
      acc += h[s] * Cf[s];
    }
    yb[(k * Lc + l) * DIc + d] = acc + Dv * xvv;
  }
}

// ---------------------------------------------------------------------------
// bias-branch epilogue: combine dirs + LN + silu(z) + out-proj -> biasb[slot].
__global__ __launch_bounds__(256) void k_out_bias(const float* onw, const float* onb,
                                                  const float* ob, float* ws) {
  __shared__ float yy[4][DIc];
  __shared__ float ml[4][DIc];
  __shared__ float mnv[4], isv[4];
  int tid = threadIdx.x;
  int slot = blockIdx.y;
  float* base = ws + (size_t)slot * SLOTF;
  const float* yb = base + OFF_Y;
  const float* zb = base + OFF_Z;
  const float* owT = ws + OFF_TW + TW_OW + 128 * 64;  // branch 1
  float* biasb = ws + OFF_BIAS;
  int l0 = blockIdx.x * 4;
  for (int it = tid; it < 4 * DIc; it += 256) {
    int d = it & (DIc - 1), p = it >> 7;
    int l = l0 + p;
    int hh = l / 48, www = l % 48;
    int lr = l, lcx = www * 48 + hh;
    float v = yb[(0 * Lc + lr) * DIc + d] + yb[(1 * Lc + lcx) * DIc + d] +
              yb[(2 * Lc + (Lc - 1 - lr)) * DIc + d] +
              yb[(3 * Lc + (Lc - 1 - lcx)) * DIc + d];
    yy[p][d] = v;
  }
  __syncthreads();
  {
    int wv = tid >> 6, c = tid & 63;
    float a = yy[wv][c], b = yy[wv][c + 64];
    float s1 = wsum(a + b);
    float s2 = wsum(a * a + b * b);
    float mu = s1 * (1.f / 128.f);
    float var = s2 * (1.f / 128.f) - mu * mu;
    if (c == 0) { mnv[wv] = mu; isv[wv] = rsqrtf(var + 1e-6f); }
  }
  __syncthreads();
  for (int it = tid; it < 4 * DIc; it += 256) {
    int d = it & (DIc - 1), p = it >> 7;
    int l = l0 + p;
    float m = (yy[p][d] - mnv[p]) * isv[p] * onw[DIc + d] + onb[DIc + d];  // branch 1
    float zv = zb[l * DIc + d];
    ml[p][d] = m * zv * sigmoidf(zv);
  }
  __syncthreads();
  {
    int p = tid >> 6, c = tid & 63;
    int l = l0 + p;
    float acc = ob[Cc + c];
    for (int d2 = 0; d2 < DIc; d2++) acc += owT[d2 * 64 + c] * ml[p][d2];
    biasb[(slot * Lc + l) * Cc + c] = acc;
  }
}

// ---------------------------------------------------------------------------
// s-branch epilogue (slot 4, branch 0): combine + LN + silu(z) + out-proj,
// state update; if fuse: KL + in-proj for next round; if finalw: write d_out.
__global__ __launch_bounds__(256) void k_out_s(const float* onw, const float* onb,
                                               const float* ob, const float* in_b,
                                               int targ, int fuse, int finalw,
                                               const float* curb, float* nxtb,
                                               float* outp, float* ws) {
  __shared__ float yy[4][DIc];
  __shared__ float ml[4][DIc];
  __shared__ float xv[4][64];
  __shared__ float mnv[4], isv[4];
  int tid = threadIdx.x;
  float* base = ws + (size_t)4 * SLOTF;
  const float* yb = base + OFF_Y;
  const float* zb = base + OFF_Z;
  float* xcpre = base + OFF_XCPRE;
  float* zbuf  = base + OFF_Z;
  const float* owT = ws + OFF_TW + TW_OW;           // branch 0
  const float* inwT = ws + OFF_TW + TW_INW;         // branch 0
  const float* biasb = ws + OFF_BIAS;
  int l0 = blockIdx.x * 4;
  for (int it = tid; it < 4 * DIc; it += 256) {
    int d = it & (DIc - 1), p = it >> 7;
    int l = l0 + p;
    int hh = l / 48, www = l % 48;
    int lr = l, lcx = www * 48 + hh;
    float v = yb[(0 * Lc + lr) * DIc + d] + yb[(1 * Lc + lcx) * DIc + d] +
              yb[(2 * Lc + (Lc - 1 - lr)) * DIc + d] +
              yb[(3 * Lc + (Lc - 1 - lcx)) * DIc + d];
    yy[p][d] = v;
  }
  __syncthreads();
  {
    int wv = tid >> 6, c = tid & 63;
    float a = yy[wv][c], b = yy[wv][c + 64];
    float s1 = wsum(a + b);
    float s2 = wsum(a * a + b * b);
    float mu = s1 * (1.f / 128.f);
    float var = s2 * (1.f / 128.f) - mu * mu;
    if (c == 0) { mnv[wv] = mu; isv[wv] = rsqrtf(var + 1e-6f); }
  }
  __syncthreads();
  for (int it = tid; it < 4 * DIc; it += 256) {
    int d = it & (DIc - 1), p = it >> 7;
    int l = l0 + p;
    float m = (yy[p][d] - mnv[p]) * isv[p] * onw[d] + onb[d];  // branch 0
    float zv = zb[l * DIc + d];
    ml[p][d] = m * zv * sigmoidf(zv);
  }
  __syncthreads();
  {
    int p = tid >> 6, c = tid & 63;
    int l = l0 + p;
    float acc = ob[c];
    for (int d2 = 0; d2 < DIc; d2++) acc += owT[d2 * 64 + c] * ml[p][d2];
    float cv = curb[l * Cc + c];
    float nv = cv * __expf(acc) + biasb[(targ * Lc + l) * Cc + c];
    nxtb[l * Cc + c] = nv;
    if (finalw) outp[c * Lc + l] = nv;
    if (fuse) {
      float mp = wmax(cv);
      float sp = wsum(__expf(cv - mp));
      float lp = cv - mp - __logf(sp);
      float mq = wmax(nv);
      float sq = wsum(__expf(nv - mq));
      float lq = nv - mq - __logf(sq);
      xv[p][c] = __expf(lp) * (lp - lq);
    }
  }
  if (fuse) {
    __syncthreads();
    int d = tid;
    float acc[4] = {0.f, 0.f, 0.f, 0.f};
    for (int cc = 0; cc < Cc; cc++) {
      float wval = inwT[cc * 256 + d];
#pragma unroll
      for (int p = 0; p < 4; p++) acc[p] += wval * xv[p][cc];
    }
    float bv = in_b[d];
    if (d < DIc) {
#pragma unroll
      for (int p = 0; p < 4; p++) xcpre[(l0 + p) * DIc + d] = acc[p] + bv;
    } else {
      int dd = d - DIc;
#pragma unroll
      for (int p = 0; p < 4; p++) zbuf[(l0 + p) * DIc + dd] = acc[p] + bv;
    }
  }
}

// ---------------------------------------------------------------------------
extern "C" void kernel_launch(void* const* d_in, const int* in_sizes, int n_in,
                              void* d_out, int out_size, void* d_ws, size_t ws_size,
                              hipStream_t stream) {
  (void)in_sizes; (void)n_in; (void)out_size; (void)ws_size;
  const float* img    = (const float*)d_in[0];
  const float* dz     = (const float*)d_in[1];
  const float* sigma  = (const float*)d_in[2];
  const float* in_w   = (const float*)d_in[3];
  const float* in_b   = (const float*)d_in[4];
  const float* conv_w = (const float*)d_in[5];
  const float* conv_b = (const float*)d_in[6];
  const float* xp_w   = (const float*)d_in[7];
  const float* dt_w   = (const float*)d_in[8];
  const float* dt_b   = (const float*)d_in[9];
  const float* A_logs = (const float*)d_in[10];
  const float* Ds     = (const float*)d_in[11];
  const float* onw    = (const float*)d_in[12];
  const float* onb    = (const float*)d_in[13];
  const float* ow     = (const float*)d_in[14];
  const float* ob     = (const float*)d_in[15];
  const float* niw    = (const float*)d_in[16];
  const float* nib    = (const float*)d_in[17];
  const float* ndw    = (const float*)d_in[18];
  const float* ndb    = (const float*)d_in[19];
  float* ws = (float*)d_ws;
  float* outp = (float*)d_out;

  hipLaunchKernelGGL(k_transpose, dim3(144), dim3(256), 0, stream, in_w, xp_w, ow,
                     conv_w, A_logs, dt_w, ws + OFF_TW);
  hipLaunchKernelGGL(k_prep, dim3(576), dim3(256), 0, stream, dz, sigma, ndw, ndb, ws);

  // mega round: bias t=0..3 (slots 0-3) + s-branch t=0 (slot 4)
  hipLaunchKernelGGL(k_inproj, dim3(288, 5), dim3(256), 0, stream, img, niw, nib, in_b, ws);
  hipLaunchKernelGGL(k_conv_proj, dim3(576, 5), dim3(256), 0, stream, conv_b, 0, ws);
  hipLaunchKernelGGL(k_scan1, dim3(288, 5), dim3(256), 0, stream, dt_b, 0, ws);
  hipLaunchKernelGGL(k_scan_mid, dim3(32, 5), dim3(256), 0, stream, 0, ws);
  hipLaunchKernelGGL(k_scan2, dim3(288, 5), dim3(256), 0, stream, dt_b, Ds, 0, ws);
  hipLaunchKernelGGL(k_out_bias, dim3(576, 4), dim3(256), 0, stream, onw, onb, ob, ws);

  // s-branch rounds; cur state alternates B1 <-> B2. k_out_s(t) fuses next inproj.
  float* b1 = ws + OFF_B1;
  float* b2 = ws + OFF_B2;
  hipLaunchKernelGGL(k_out_s, dim3(576), dim3(256), 0, stream, onw, onb, ob, in_b,
                     0, 1, 0, (const float*)b1, b2, outp, ws);
  for (int t = 1; t < Tc; t++) {
    const float* curb = (t & 1) ? b2 : b1;
    float* nxtb       = (t & 1) ? b1 : b2;
    hipLaunchKernelGGL(k_conv_proj, dim3(576, 1), dim3(256), 0, stream, conv_b, 4, ws);
    hipLaunchKernelGGL(k_scan1, dim3(288, 1), dim3(256), 0, stream, dt_b, 4, ws);
    hipLaunchKernelGGL(k_scan_mid, dim3(32, 1), dim3(256), 0, stream, 4, ws);
    hipLaunchKernelGGL(k_scan2, dim3(288, 1), dim3(256), 0, stream, dt_b, Ds, 4, ws);
    hipLaunchKernelGGL(k_out_s, dim3(576), dim3(256), 0, stream, onw, onb, ob, in_b,
                       t, (t == Tc - 1) ? 0 : 1, (t == Tc - 1) ? 1 : 0,
                       curb, nxtb, outp, ws);
  }
}